// Round 9
// baseline (76926.959 us; speedup 1.0000x reference)
//
#include <hip/hip_runtime.h>
#include <math.h>

// Persistent cooperative LSTM: 256 WGs x 512 threads, 1 WG/CU.
// WG w owns hidden units [8w, 8w+8). wave u = unit, 16-lane group g = gate.
// Folded weights W' = W_hh + (w1+w2)(x)W_lin (128/thread; unified VGPR/AGPR
// file holds them — R6 proved residency).
//
// R9 change vs R7 (single-variable): CONSUMER POLL.
//   R7: 4 x 8B agent-scope ATOMIC loads per thread (strided). Theory: atomic
//   vmem ops don't lane-coalesce -> ~256 serialized TA ops per wave per poll
//   iteration -> poll period ~1000+ cyc, dominating the step.
//   R9: plain (default-cached) global_load_dwordx4 x2 = 32B contiguous per
//   thread, wave-coalesced; per-8B tags embedded in the data validate each
//   word; on stale check -> __builtin_amdgcn_fence(ACQUIRE, "agent")
//   (compiler-guaranteed L1 invalidate) -> retry. Progress proof: post-fence
//   loads are serviced >= L2; L2 staleness is cleared by the producer's
//   agent-scope store invalidation (mechanism proven by R1-R7 passing).
//   No hand-guessed cache flags (R8 lesson: that way lies deadlock).
//
// Producer (R7, proven): last-arriving wave (LDS election) stores ONE 64B
// full line of 8 fused ((t+1)<<32 | f32bits(h)) words, agent scope.
// One __syncthreads per step. Exact-tag match + parity double buffer = no
// ABA; per-launch memset kills graph-replay staleness.
//
// y_t: owner WG (t%256) dots pulled registers with W_lin into LDS y_acc;
// owner's wave7 writes out[t] during step t+1 (off the critical path).

#define HDIM 2048
#define TSTEPS 4096
#define NWG 256
#define NTH 512  // 8 waves

typedef unsigned long long u64;
typedef unsigned int u32;
typedef __attribute__((ext_vector_type(4))) u32 u32x4;

__device__ __forceinline__ float sigmoidf_(float x) {
    return 1.0f / (1.0f + expf(-x));
}

// 32B contiguous poll read: two dwordx4 loads, default caching (plain-load
// semantics), single vmcnt wait. Tags inside the payload self-validate.
__device__ __forceinline__ void poll_load32(const u64* p, u32x4& r0, u32x4& r1) {
    asm volatile("global_load_dwordx4 %0, %2, off\n\t"
                 "global_load_dwordx4 %1, %2, off offset:16\n\t"
                 "s_waitcnt vmcnt(0)"
                 : "=&v"(r0), "=&v"(r1) : "v"(p) : "memory");
}

__global__ __launch_bounds__(NTH, 2)
void weld_lstm_persistent(const float* __restrict__ src,
                          const float* __restrict__ W_ih,
                          const float* __restrict__ W_hh,
                          const float* __restrict__ b_ih,
                          const float* __restrict__ b_hh,
                          const float* __restrict__ W_lin,
                          const float* __restrict__ b_lin,
                          float* __restrict__ out,
                          u64* __restrict__ h_buf)
{
    __shared__ float h_lds[2][HDIM];
    __shared__ float s_lds[TSTEPS];
    __shared__ float wlin_lds[HDIM];
    __shared__ float hshare[8];   // this WG's 8 fresh h values
    __shared__ int   arrive_cnt;  // monotonic arrival counter (8 per step)
    __shared__ float y_acc;

    const int wg   = blockIdx.x;
    const int tid  = threadIdx.x;
    const int wave = tid >> 6;
    const int lane = tid & 63;
    const int g    = lane >> 4;        // gate 0..3 (i,f,g,o)
    const int sub  = lane & 15;
    const int unit = wg * 8 + wave;
    const int row  = g * HDIM + unit;

    for (int i = tid; i < TSTEPS; i += NTH) s_lds[i] = src[3 * i];
    for (int i = tid; i < HDIM;   i += NTH) wlin_lds[i] = W_lin[i];
    if (tid == 0) { y_acc = 0.0f; arrive_cnt = 0; }

    const float s01  = src[1];
    const float s02  = src[2];
    const float blin = b_lin[0];

    const float w0    = W_ih[row * 3 + 0];
    const float w1    = W_ih[row * 3 + 1];
    const float w2    = W_ih[row * 3 + 2];
    const float w12   = w1 + w2;
    const float braw  = b_ih[row] + b_hh[row];
    const float bfold = braw + w12 * blin;

    // Folded weights W'[row,c] = W_hh[row,c] + w12*W_lin[c]; this lane's
    // columns: c = k*64 + sub*4 + {0..3}, k = 0..31.
    float wreg[128];
    {
        const float* wrow = W_hh + (size_t)row * HDIM;
        #pragma unroll
        for (int k = 0; k < 32; ++k) {
            const int c = k * 64 + sub * 4;
            float4 wv = *reinterpret_cast<const float4*>(wrow + c);
            float4 lv = *reinterpret_cast<const float4*>(W_lin + c);
            wreg[k * 4 + 0] = wv.x + w12 * lv.x;
            wreg[k * 4 + 1] = wv.y + w12 * lv.y;
            wreg[k * 4 + 2] = wv.z + w12 * lv.z;
            wreg[k * 4 + 3] = wv.w + w12 * lv.w;
        }
    }

    __syncthreads();

    float c_state = 0.0f;

    // consumer pull mapping: thread pulls units [tid*4, tid*4+4) (32B)
    const int cb = tid * 4;
    const float4 wlc = *reinterpret_cast<const float4*>(&wlin_lds[cb]);

    for (int t = 0; t < TSTEPS; ++t) {
        const int wb = t & 1;       // buffer receiving h_t
        const int rb = wb ^ 1;      // buffer holding h_{t-1} (t>=1)

        float xterm;
        if (t == 0) {
            xterm = braw + w0 * s_lds[0] + w1 * s01 + w2 * s02;
        } else {
            xterm = bfold + w0 * s_lds[t];
        }

        float sum = 0.0f;
        if (t > 0) {
            float a0 = 0.0f, a1 = 0.0f, a2 = 0.0f, a3 = 0.0f;
            #pragma unroll
            for (int k = 0; k < 32; ++k) {
                const int col = k * 64 + sub * 4;
                float4 h4 = *reinterpret_cast<const float4*>(&h_lds[rb][col]);
                a0 += wreg[k * 4 + 0] * h4.x;
                a1 += wreg[k * 4 + 1] * h4.y;
                a2 += wreg[k * 4 + 2] * h4.z;
                a3 += wreg[k * 4 + 3] * h4.w;
            }
            sum = (a0 + a1) + (a2 + a3);
            sum += __shfl_xor(sum, 1);
            sum += __shfl_xor(sum, 2);
            sum += __shfl_xor(sum, 4);
            sum += __shfl_xor(sum, 8);
        }

        // finalize y_{t-1}: owner of step t-1, after iter t-1's barrier
        if (t > 0 && wg == ((t - 1) & (NWG - 1)) && wave == 7 && lane == 0) {
            out[t - 1] = y_acc + blin;
            y_acc = 0.0f;  // next partials for this WG arrive at step t+255
        }

        const float gate = sum + xterm;
        const float gi = __shfl(gate, 0);
        const float gf = __shfl(gate, 16);
        const float gg = __shfl(gate, 32);
        const float go = __shfl(gate, 48);
        c_state = sigmoidf_(gf) * c_state + sigmoidf_(gi) * tanhf(gg);
        const float h_new = sigmoidf_(go) * tanhf(c_state);

        // ---- publish (R7): gather 8 values in LDS, last-arriving wave does
        //      ONE coalesced full-line (64B) store of fused tag|value words --
        u64* hb = h_buf + (size_t)wb * HDIM;
        int is_storer = 0;
        if (lane == 0) {
            hshare[wave] = h_new;
            const int old = __hip_atomic_fetch_add(
                &arrive_cnt, 1, __ATOMIC_ACQ_REL,
                __HIP_MEMORY_SCOPE_WORKGROUP);
            is_storer = (old == 8 * t + 7);
        }
        is_storer = __shfl(is_storer, 0);
        if (is_storer && lane < 8) {
            const u64 p = ((u64)(unsigned)(t + 1) << 32) |
                          (u64)__float_as_uint(hshare[lane]);
            __hip_atomic_store(&hb[wg * 8 + lane], p,
                               __ATOMIC_RELAXED, __HIP_MEMORY_SCOPE_AGENT);
        }

        // ---- poll: coalesced 32B plain loads + acquire-agent fence retry --
        const u32 want = (u32)(t + 1);
        u32x4 r0, r1;
        const u64* pp = hb + cb;
        for (;;) {
            poll_load32(pp, r0, r1);
            if (r0.y == want && r0.w == want && r1.y == want && r1.w == want)
                break;
            __builtin_amdgcn_s_sleep(1);  // ~64 cycles
            // compiler-guaranteed L1 invalidate: next loads serviced >= L2
            __builtin_amdgcn_fence(__ATOMIC_ACQUIRE, "agent");
        }
        const float f0 = __uint_as_float(r0.x);
        const float f1 = __uint_as_float(r0.z);
        const float f2 = __uint_as_float(r1.x);
        const float f3 = __uint_as_float(r1.z);
        float4 hv; hv.x = f0; hv.y = f1; hv.z = f2; hv.w = f3;
        *reinterpret_cast<float4*>(&h_lds[wb][cb]) = hv;

        // y_t partials from registers (owner WG only; off critical path)
        if (wg == (t & (NWG - 1))) {
            float yp = f0 * wlc.x + f1 * wlc.y + f2 * wlc.z + f3 * wlc.w;
            yp += __shfl_xor(yp, 1);
            yp += __shfl_xor(yp, 2);
            yp += __shfl_xor(yp, 4);
            yp += __shfl_xor(yp, 8);
            yp += __shfl_xor(yp, 16);
            yp += __shfl_xor(yp, 32);
            if (lane == 0) atomicAdd(&y_acc, yp);
        }

        __syncthreads();  // h_lds[wb] complete; also orders y_acc partials
    }

    // final y_{T-1}: owner wg = 255
    if (wg == ((TSTEPS - 1) & (NWG - 1)) && wave == 7 && lane == 0) {
        out[TSTEPS - 1] = y_acc + blin;
    }
}

extern "C" void kernel_launch(void* const* d_in, const int* in_sizes, int n_in,
                              void* d_out, int out_size, void* d_ws, size_t ws_size,
                              hipStream_t stream) {
    const float* src   = (const float*)d_in[0];
    const float* W_ih  = (const float*)d_in[1];
    const float* W_hh  = (const float*)d_in[2];
    const float* b_ih  = (const float*)d_in[3];
    const float* b_hh  = (const float*)d_in[4];
    const float* W_lin = (const float*)d_in[5];
    const float* b_lin = (const float*)d_in[6];
    float* out = (float*)d_out;

    // ws: [0, 32 KiB) = h_buf: 2 (parity) x 2048 x 8 B packed tag|value.
    // Cleared every launch so stale tags from a previous replay can't match.
    u64* h_buf = (u64*)d_ws;
    hipMemsetAsync(d_ws, 0, 2 * HDIM * sizeof(u64), stream);

    void* args[] = { &src, &W_ih, &W_hh, &b_ih, &b_hh, &W_lin, &b_lin,
                     &out, &h_buf };
    hipLaunchCooperativeKernel((const void*)weld_lstm_persistent,
                               dim3(NWG), dim3(NTH), args, 0, stream);
}

// Round 10
// 13424.031 us; speedup vs baseline: 5.7305x; 5.7305x over previous
//
#include <hip/hip_runtime.h>
#include <math.h>

// Persistent cooperative LSTM: 256 WGs x 512 threads, 1 WG/CU.
// WG w owns hidden units [8w, 8w+8). wave u = unit, 16-lane group g = gate.
// Folded weights W' = W_hh + (w1+w2) (x) W_lin (128/thread, compiler-managed).
//
// == This is R7 verbatim (best measured: 13.4 ms), restored after R8 (relay,
// == deadlock on unverified cache semantics) and R9 (fence-poll, 5.7x
// == regression from CU-wide L1-invalidate storms) refuted both "improve the
// == detect leg" theories. Agent-scope atomics are the proven sync primitive.
//
// Producer: 8 waves' h values gathered in LDS; a monotonic LDS fetch_add
// elects the LAST-arriving wave (no barrier, no spin); its lanes 0-7 issue
// ONE wave-coalesced 64B full-line store of 8 fused ((t+1)<<32|f32bits(h))
// words (agent scope). Full-line write -> no partial-line RMW serialization
// (this was the R4->R7 2x win; WRITE_SIZE 262->65 MB).
//
// Consumer: all threads poll 4 coalesced units (wave*256+lane+64j) with
// agent-scope 8B atomic loads until tag==t+1 (s_sleep-throttled), write
// h_lds[t&1], ONE __syncthreads, next matvec reads h_lds. Exact-tag match +
// per-parity buffers kill ABA; per-launch memset kills graph-replay
// staleness. Polls are served from XCD-local L2 between producer
// invalidations (FETCH ~= 8 XCDs x 16 KB/step = broadcast minimum).
//
// y_t: owner WG (t%256) dots pulled registers with W_lin into LDS y_acc;
// its wave7 writes out[t] during step t+1 (off the critical path).

#define HDIM 2048
#define TSTEPS 4096
#define NWG 256
#define NTH 512  // 8 waves

typedef unsigned long long u64;
typedef unsigned int u32;

__device__ __forceinline__ float sigmoidf_(float x) {
    return 1.0f / (1.0f + expf(-x));
}

__global__ __launch_bounds__(NTH, 2)
void weld_lstm_persistent(const float* __restrict__ src,
                          const float* __restrict__ W_ih,
                          const float* __restrict__ W_hh,
                          const float* __restrict__ b_ih,
                          const float* __restrict__ b_hh,
                          const float* __restrict__ W_lin,
                          const float* __restrict__ b_lin,
                          float* __restrict__ out,
                          u64* __restrict__ h_buf)
{
    __shared__ float h_lds[2][HDIM];
    __shared__ float s_lds[TSTEPS];
    __shared__ float wlin_lds[HDIM];
    __shared__ float hshare[8];   // this WG's 8 fresh h values
    __shared__ int   arrive_cnt;  // monotonic arrival counter (8 per step)
    __shared__ float y_acc;

    const int wg   = blockIdx.x;
    const int tid  = threadIdx.x;
    const int wave = tid >> 6;
    const int lane = tid & 63;
    const int g    = lane >> 4;        // gate 0..3 (i,f,g,o)
    const int sub  = lane & 15;
    const int unit = wg * 8 + wave;
    const int row  = g * HDIM + unit;

    for (int i = tid; i < TSTEPS; i += NTH) s_lds[i] = src[3 * i];
    for (int i = tid; i < HDIM;   i += NTH) wlin_lds[i] = W_lin[i];
    if (tid == 0) { y_acc = 0.0f; arrive_cnt = 0; }

    const float s01  = src[1];
    const float s02  = src[2];
    const float blin = b_lin[0];

    const float w0    = W_ih[row * 3 + 0];
    const float w1    = W_ih[row * 3 + 1];
    const float w2    = W_ih[row * 3 + 2];
    const float w12   = w1 + w2;
    const float braw  = b_ih[row] + b_hh[row];
    const float bfold = braw + w12 * blin;

    // Folded weights W'[row,c] = W_hh[row,c] + w12*W_lin[c]; this lane's
    // columns: c = k*64 + sub*4 + {0..3}, k = 0..31.
    float wreg[128];
    {
        const float* wrow = W_hh + (size_t)row * HDIM;
        #pragma unroll
        for (int k = 0; k < 32; ++k) {
            const int c = k * 64 + sub * 4;
            float4 wv = *reinterpret_cast<const float4*>(wrow + c);
            float4 lv = *reinterpret_cast<const float4*>(W_lin + c);
            wreg[k * 4 + 0] = wv.x + w12 * lv.x;
            wreg[k * 4 + 1] = wv.y + w12 * lv.y;
            wreg[k * 4 + 2] = wv.z + w12 * lv.z;
            wreg[k * 4 + 3] = wv.w + w12 * lv.w;
        }
    }

    __syncthreads();

    float c_state = 0.0f;

    const int pbase = wave * 256 + lane;  // coalesced pull mapping
    const float wl0 = wlin_lds[pbase +   0];
    const float wl1 = wlin_lds[pbase +  64];
    const float wl2 = wlin_lds[pbase + 128];
    const float wl3 = wlin_lds[pbase + 192];

    for (int t = 0; t < TSTEPS; ++t) {
        const int wb = t & 1;       // buffer receiving h_t
        const int rb = wb ^ 1;      // buffer holding h_{t-1} (t>=1)

        float xterm;
        if (t == 0) {
            xterm = braw + w0 * s_lds[0] + w1 * s01 + w2 * s02;
        } else {
            xterm = bfold + w0 * s_lds[t];
        }

        float sum = 0.0f;
        if (t > 0) {
            float a0 = 0.0f, a1 = 0.0f, a2 = 0.0f, a3 = 0.0f;
            #pragma unroll
            for (int k = 0; k < 32; ++k) {
                const int col = k * 64 + sub * 4;
                float4 h4 = *reinterpret_cast<const float4*>(&h_lds[rb][col]);
                a0 += wreg[k * 4 + 0] * h4.x;
                a1 += wreg[k * 4 + 1] * h4.y;
                a2 += wreg[k * 4 + 2] * h4.z;
                a3 += wreg[k * 4 + 3] * h4.w;
            }
            sum = (a0 + a1) + (a2 + a3);
            sum += __shfl_xor(sum, 1);
            sum += __shfl_xor(sum, 2);
            sum += __shfl_xor(sum, 4);
            sum += __shfl_xor(sum, 8);
        }

        // finalize y_{t-1}: owner of step t-1, after iter t-1's barrier
        if (t > 0 && wg == ((t - 1) & (NWG - 1)) && wave == 7 && lane == 0) {
            out[t - 1] = y_acc + blin;
            y_acc = 0.0f;  // next partials for this WG arrive at step t+255
        }

        const float gate = sum + xterm;
        const float gi = __shfl(gate, 0);
        const float gf = __shfl(gate, 16);
        const float gg = __shfl(gate, 32);
        const float go = __shfl(gate, 48);
        c_state = sigmoidf_(gf) * c_state + sigmoidf_(gi) * tanhf(gg);
        const float h_new = sigmoidf_(go) * tanhf(c_state);

        // ---- publish: gather 8 values in LDS, last-arriving wave does ONE
        //      coalesced full-line (64B) store of fused tag|value words ----
        u64* hb = h_buf + (size_t)wb * HDIM;
        int is_storer = 0;
        if (lane == 0) {
            hshare[wave] = h_new;
            // acq_rel: orders the hshare write before the counter bump, and
            // makes the winner's subsequent hshare reads see all 8 writes
            const int old = __hip_atomic_fetch_add(
                &arrive_cnt, 1, __ATOMIC_ACQ_REL,
                __HIP_MEMORY_SCOPE_WORKGROUP);
            is_storer = (old == 8 * t + 7);
        }
        is_storer = __shfl(is_storer, 0);
        if (is_storer && lane < 8) {
            const u64 p = ((u64)(unsigned)(t + 1) << 32) |
                          (u64)__float_as_uint(hshare[lane]);
            // lanes 0-7: 8B-consecutive -> one 64B full-line transaction
            __hip_atomic_store(&hb[wg * 8 + lane], p,
                               __ATOMIC_RELAXED, __HIP_MEMORY_SCOPE_AGENT);
        }

        // pull 4 coalesced units of h_t (512 B contiguous per wave per instr)
        const unsigned want = (unsigned)(t + 1);
        u64 v0, v1, v2, v3;
        for (;;) {
            v0 = __hip_atomic_load(&hb[pbase +   0], __ATOMIC_RELAXED, __HIP_MEMORY_SCOPE_AGENT);
            v1 = __hip_atomic_load(&hb[pbase +  64], __ATOMIC_RELAXED, __HIP_MEMORY_SCOPE_AGENT);
            v2 = __hip_atomic_load(&hb[pbase + 128], __ATOMIC_RELAXED, __HIP_MEMORY_SCOPE_AGENT);
            v3 = __hip_atomic_load(&hb[pbase + 192], __ATOMIC_RELAXED, __HIP_MEMORY_SCOPE_AGENT);
            if ((unsigned)(v0 >> 32) == want && (unsigned)(v1 >> 32) == want &&
                (unsigned)(v2 >> 32) == want && (unsigned)(v3 >> 32) == want)
                break;
            __builtin_amdgcn_s_sleep(1);  // ~64 cycles
        }
        const float f0 = __uint_as_float((unsigned)v0);
        const float f1 = __uint_as_float((unsigned)v1);
        const float f2 = __uint_as_float((unsigned)v2);
        const float f3 = __uint_as_float((unsigned)v3);
        h_lds[wb][pbase +   0] = f0;
        h_lds[wb][pbase +  64] = f1;
        h_lds[wb][pbase + 128] = f2;
        h_lds[wb][pbase + 192] = f3;

        // y_t partials from registers (owner WG only; off critical path)
        if (wg == (t & (NWG - 1))) {
            float yp = f0 * wl0 + f1 * wl1 + f2 * wl2 + f3 * wl3;
            yp += __shfl_xor(yp, 1);
            yp += __shfl_xor(yp, 2);
            yp += __shfl_xor(yp, 4);
            yp += __shfl_xor(yp, 8);
            yp += __shfl_xor(yp, 16);
            yp += __shfl_xor(yp, 32);
            if (lane == 0) atomicAdd(&y_acc, yp);
        }

        __syncthreads();  // h_lds[wb] complete; also orders y_acc partials
    }

    // final y_{T-1}: owner wg = 255
    if (wg == ((TSTEPS - 1) & (NWG - 1)) && wave == 7 && lane == 0) {
        out[TSTEPS - 1] = y_acc + blin;
    }
}

extern "C" void kernel_launch(void* const* d_in, const int* in_sizes, int n_in,
                              void* d_out, int out_size, void* d_ws, size_t ws_size,
                              hipStream_t stream) {
    const float* src   = (const float*)d_in[0];
    const float* W_ih  = (const float*)d_in[1];
    const float* W_hh  = (const float*)d_in[2];
    const float* b_ih  = (const float*)d_in[3];
    const float* b_hh  = (const float*)d_in[4];
    const float* W_lin = (const float*)d_in[5];
    const float* b_lin = (const float*)d_in[6];
    float* out = (float*)d_out;

    // ws: [0, 32 KiB) = h_buf: 2 (parity) x 2048 x 8 B packed tag|value.
    // Cleared every launch so stale tags from a previous replay can't match.
    u64* h_buf = (u64*)d_ws;
    hipMemsetAsync(d_ws, 0, 2 * HDIM * sizeof(u64), stream);

    void* args[] = { &src, &W_ih, &W_hh, &b_ih, &b_hh, &W_lin, &b_lin,
                     &out, &h_buf };
    hipLaunchCooperativeKernel((const void*)weld_lstm_persistent,
                               dim3(NWG), dim3(NTH), args, 0, stream);
}